// Round 14
// baseline (725.262 us; speedup 1.0000x reference)
//
#include <hip/hip_runtime.h>
#include <cstddef>
#include <cstdint>

#define TOK    49      // tokens (7x7)
#define KD     32      // key dim
#define NH     8       // heads
#define DHEAD  128     // v head dim
#define HQKV   1536    // qkv channels
#define DHTOT  1024    // NH*DHEAD
#define DIMM   384     // model dim

typedef unsigned short u16;
typedef float  f32x4  __attribute__((ext_vector_type(4)));
typedef __bf16 bf16x8 __attribute__((ext_vector_type(8)));

typedef const __attribute__((address_space(1))) void gas_void;
typedef __attribute__((address_space(3))) void las_void;

static __device__ __forceinline__ u16 f2bf(float f) {
    unsigned int u = __builtin_bit_cast(unsigned int, f);
    return (u16)((u + 0x7fffu + ((u >> 16) & 1u)) >> 16);   // RNE
}

// XOR-swizzled index into a row-major [*][64] bf16 LDS image (QKs/Ps).
static __device__ __forceinline__ int swz(int row, int c) {
    return (row << 6) + ((((c >> 3) ^ (row & 7)) << 3) | (c & 7));
}

// Vts swizzle (validated r13): XOR both row&7 and (row>>3)&7 — V scatter
// writes 2-way, PV reads ~2-way.
static __device__ __forceinline__ int swzV(int row, int c) {
    return (row << 6) + ((((c >> 3) ^ (row & 7) ^ ((row >> 3) & 7)) << 3) | (c & 7));
}

// Bijective XCD-chunked remap (m204).
static __device__ __forceinline__ int xcd_chunk(int bid, int nwg) {
    const int xcd = bid & 7, slot = bid >> 3;
    const int q = nwg >> 3, r = nwg & 7;
    return (xcd < r ? xcd * (q + 1) : r * (q + 1) + (xcd - r) * q) + slot;
}

#define BAR() __builtin_amdgcn_s_barrier()
#define WAIT_VM8() asm volatile("s_waitcnt vmcnt(8)" ::: "memory")
#define WAIT_VM0() asm volatile("s_waitcnt vmcnt(0)" ::: "memory")
// Barrier that does NOT drain vmcnt: LDS writes visible, global loads stay in flight.
#define LGKM0_BAR() do { asm volatile("s_waitcnt lgkmcnt(0)" ::: "memory"); \
                         __builtin_amdgcn_s_barrier(); } while (0)

// ---------------------------------------------------------------------------
// fp32 -> bf16 cast with T2 pre-swizzle (validated r10-r13).
// ---------------------------------------------------------------------------
__global__ __launch_bounds__(256)
void cast_swz(const float* __restrict__ in, u16* __restrict__ out, int K8, long nchunk)
{
    long i = (long)blockIdx.x * 256 + threadIdx.x;
    const long stride = (long)gridDim.x * 256;
    for (; i < nchunk; i += stride) {
        const long row = i / K8;
        const int  c8  = (int)(i - row * K8);
        const int  slot = c8 & 7, tpan = c8 >> 3;
        float4 v0 = reinterpret_cast<const float4*>(in)[i * 2];
        float4 v1 = reinterpret_cast<const float4*>(in)[i * 2 + 1];
        uint4 o;
        o.x = f2bf(v0.x) | ((unsigned)f2bf(v0.y) << 16);
        o.y = f2bf(v0.z) | ((unsigned)f2bf(v0.w) << 16);
        o.z = f2bf(v1.x) | ((unsigned)f2bf(v1.y) << 16);
        o.w = f2bf(v1.z) | ((unsigned)f2bf(v1.w) << 16);
        *reinterpret_cast<uint4*>(out + row * (long)K8 * 8 + tpan * 64 +
                                  ((slot ^ ((int)row & 7)) << 3)) = o;
    }
}

// ---------------------------------------------------------------------------
// bias_full[h][n*49+m] = attn_bias[h][bias_idxs[n*49+m]]
// ---------------------------------------------------------------------------
__global__ __launch_bounds__(256)
void bias_expand(const float* __restrict__ attn_bias, const int* __restrict__ idxs,
                 float* __restrict__ bias_full, int n_off)
{
    int i = blockIdx.x * 256 + threadIdx.x;
    if (i < NH * TOK * TOK) {
        int h = i / (TOK * TOK), s = i - h * (TOK * TOK);
        bias_full[i] = attn_bias[h * n_off + idxs[s]];
    }
}

static __device__ __forceinline__ int frag_off(int row, int ks8fg) {
    return (row << 6) + (((ks8fg ^ (row & 7)) << 3));
}

// ---------------------------------------------------------------------------
// QKV GEMM (validated r12/r13): T4 K-loop, plain row-major bf16 out.
// ---------------------------------------------------------------------------
__global__ __launch_bounds__(256)
void gemm_qkv(const u16* __restrict__ A,      // [M][384] bf16 pre-swz
              const u16* __restrict__ W,      // [1536][384] bf16 pre-swz
              const float* __restrict__ bias, // [1536]
              u16* __restrict__ qkvb, int M)
{
    const int K = DIMM;
    const int NB = HQKV / 128;
    const int nwg = (M / 128) * NB;
    const int wgid = xcd_chunk(blockIdx.x, nwg);
    const int bm = (wgid / NB) * 128;
    const int bn = (wgid % NB) * 128;

    __shared__ u16 Alds[2][128 * 64];
    __shared__ u16 Blds[2][128 * 64];

    const int t    = threadIdx.x;
    const int lane = t & 63;
    const int wv   = t >> 6;
    const int wr   = wv >> 1;
    const int wc   = wv & 1;

    const int lrow = lane >> 3;
    const int lcol = (lane & 7) * 8;
    const int frow = lane & 15;
    const int fg   = lane >> 4;

    f32x4 acc[4][4];
    #pragma unroll
    for (int mi = 0; mi < 4; ++mi)
        #pragma unroll
        for (int ni = 0; ni < 4; ++ni) acc[mi][ni] = (f32x4)0.0f;

    auto STAGE = [&](int buf, int k0) {
        #pragma unroll
        for (int i = 0; i < 4; ++i) {
            const int c   = i * 4 + wv;
            const int row = c * 8 + lrow;
            __builtin_amdgcn_global_load_lds((gas_void*)(A + (size_t)(bm + row) * K + k0 + lcol),
                                             (las_void*)(&Alds[buf][c * 512]), 16, 0, 0);
            __builtin_amdgcn_global_load_lds((gas_void*)(W + (size_t)(bn + row) * K + k0 + lcol),
                                             (las_void*)(&Blds[buf][c * 512]), 16, 0, 0);
        }
    };

    STAGE(0, 0);
    STAGE(1, 64);

    const int NT = 6;
    for (int ts = 0; ts < NT; ++ts) {
        if (ts < NT - 1) { WAIT_VM8(); }
        else             { WAIT_VM0(); }
        BAR();
        const u16* Ab = Alds[ts & 1];
        const u16* Bb = Blds[ts & 1];
        #pragma unroll
        for (int ks = 0; ks < 2; ++ks) {
            const int sl = ks * 4 + fg;
            bf16x8 af[4], bf[4];
            #pragma unroll
            for (int mi = 0; mi < 4; ++mi)
                af[mi] = *reinterpret_cast<const bf16x8*>(&Ab[frag_off(wr * 64 + mi * 16 + frow, sl)]);
            #pragma unroll
            for (int ni = 0; ni < 4; ++ni)
                bf[ni] = *reinterpret_cast<const bf16x8*>(&Bb[frag_off(wc * 64 + ni * 16 + frow, sl)]);
            #pragma unroll
            for (int mi = 0; mi < 4; ++mi)
                #pragma unroll
                for (int ni = 0; ni < 4; ++ni)
                    acc[mi][ni] = __builtin_amdgcn_mfma_f32_16x16x32_bf16(af[mi], bf[ni], acc[mi][ni], 0, 0, 0);
        }
        BAR();
        if (ts < NT - 2) STAGE(ts & 1, (ts + 2) * 64);
    }

    const int rbase = (lane >> 4) * 4;
    #pragma unroll
    for (int ni = 0; ni < 4; ++ni) {
        const int col = bn + wc * 64 + ni * 16 + frow;
        const float bv = bias[col];
        #pragma unroll
        for (int mi = 0; mi < 4; ++mi) {
            #pragma unroll
            for (int j = 0; j < 4; ++j) {
                const int row = bm + wr * 64 + mi * 16 + rbase + j;
                qkvb[(size_t)row * HQKV + col] = f2bf(acc[mi][ni][j] + bv);
            }
        }
    }
}

// ---------------------------------------------------------------------------
// Proj GEMM (validated r12/r13).
// ---------------------------------------------------------------------------
__global__ __launch_bounds__(256)
void gemm_bf16_nt(const u16* __restrict__ A, const u16* __restrict__ W,
                  const float* __restrict__ bias, float* __restrict__ C,
                  int M, int N, int K)
{
    const int NB = N / 128;
    const int nwg = (M / 128) * NB;
    const int wgid = xcd_chunk(blockIdx.x, nwg);
    const int bm = (wgid / NB) * 128;
    const int bn = (wgid % NB) * 128;

    __shared__ u16 Alds[2][128 * 64];
    __shared__ u16 Blds[2][128 * 64];

    const int t    = threadIdx.x;
    const int lane = t & 63;
    const int wv   = t >> 6;
    const int wr   = wv >> 1;
    const int wc   = wv & 1;

    const int lrow = lane >> 3;
    const int lcol = (lane & 7) * 8;
    const int frow = lane & 15;
    const int fg   = lane >> 4;

    f32x4 acc[4][4];
    #pragma unroll
    for (int mi = 0; mi < 4; ++mi)
        #pragma unroll
        for (int ni = 0; ni < 4; ++ni) acc[mi][ni] = (f32x4)0.0f;

    auto STAGE = [&](int buf, int k0) {
        #pragma unroll
        for (int i = 0; i < 4; ++i) {
            const int c   = i * 4 + wv;
            const int row = c * 8 + lrow;
            __builtin_amdgcn_global_load_lds((gas_void*)(A + (size_t)(bm + row) * K + k0 + lcol),
                                             (las_void*)(&Alds[buf][c * 512]), 16, 0, 0);
            __builtin_amdgcn_global_load_lds((gas_void*)(W + (size_t)(bn + row) * K + k0 + lcol),
                                             (las_void*)(&Blds[buf][c * 512]), 16, 0, 0);
        }
    };

    const int NT = K / 64;
    STAGE(0, 0);
    STAGE(1, 64);

    for (int ts = 0; ts < NT; ++ts) {
        if (ts < NT - 1) { WAIT_VM8(); }
        else             { WAIT_VM0(); }
        BAR();
        const u16* Ab = Alds[ts & 1];
        const u16* Bb = Blds[ts & 1];
        #pragma unroll
        for (int ks = 0; ks < 2; ++ks) {
            const int sl = ks * 4 + fg;
            bf16x8 af[4], bf[4];
            #pragma unroll
            for (int mi = 0; mi < 4; ++mi)
                af[mi] = *reinterpret_cast<const bf16x8*>(&Ab[frag_off(wr * 64 + mi * 16 + frow, sl)]);
            #pragma unroll
            for (int ni = 0; ni < 4; ++ni)
                bf[ni] = *reinterpret_cast<const bf16x8*>(&Bb[frag_off(wc * 64 + ni * 16 + frow, sl)]);
            #pragma unroll
            for (int mi = 0; mi < 4; ++mi)
                #pragma unroll
                for (int ni = 0; ni < 4; ++ni)
                    acc[mi][ni] = __builtin_amdgcn_mfma_f32_16x16x32_bf16(af[mi], bf[ni], acc[mi][ni], 0, 0, 0);
        }
        BAR();
        if (ts < NT - 2) STAGE(ts & 1, (ts + 2) * 64);
    }

    const int rbase = (lane >> 4) * 4;
    #pragma unroll
    for (int ni = 0; ni < 4; ++ni) {
        const int col = bn + wc * 64 + ni * 16 + frow;
        const float bv = bias[col];
        #pragma unroll
        for (int mi = 0; mi < 4; ++mi) {
            #pragma unroll
            for (int j = 0; j < 4; ++j) {
                const int row = bm + wr * 64 + mi * 16 + rbase + j;
                C[(size_t)row * N + col] = acc[mi][ni][j] + bv;
            }
        }
    }
}

// ---------------------------------------------------------------------------
// Attention v2: one block per BATCH, 256 thr / 4 waves, 8-head loop with
// double-buffered QKs/Vts and reg-staged pipelined gather. Per-head math is
// byte-identical to r13 (validated). Barriers are lgkmcnt(0)+s_barrier so
// next head's global loads stay in flight across compute.
// ---------------------------------------------------------------------------
#define NCH 5  // ceil(49*24 / 256)

struct Regs { uint4 v[NCH]; };

static __device__ __forceinline__ void load_regs(Regs& r, const u16* __restrict__ base, int t)
{
    #pragma unroll
    for (int k = 0; k < NCH; ++k) {
        const int idx = t + k * 256;
        if (idx < TOK * 24) {
            const int n = idx / 24, c = idx - n * 24;
            r.v[k] = *reinterpret_cast<const uint4*>(base + (size_t)n * HQKV + c * 8);
        }
    }
}

static __device__ __forceinline__ void write_lds(const Regs& r, u16* __restrict__ QK,
                                                 u16* __restrict__ V, int t)
{
    #pragma unroll
    for (int k = 0; k < NCH; ++k) {
        const int idx = t + k * 256;
        if (idx < TOK * 24) {
            const int n = idx / 24, c24 = idx - n * 24;
            if (c24 < 8) {
                *reinterpret_cast<uint4*>(&QK[(n << 6) + ((c24 ^ (n & 7)) << 3)]) = r.v[k];
            } else {
                const int d0 = (c24 - 8) * 8;
                u16 vals[8];
                *reinterpret_cast<uint4*>(vals) = r.v[k];
                #pragma unroll
                for (int e = 0; e < 8; ++e)
                    V[swzV(d0 + e, n)] = vals[e];
            }
        }
    }
}

static __device__ __forceinline__ void attn_head(
    const u16* __restrict__ QK, const u16* __restrict__ V,
    float* __restrict__ S, u16* __restrict__ Ps,
    const float* __restrict__ bh_bias, u16* __restrict__ ab,
    int b, int h, int t)
{
    const int lane = t & 63;
    const int w    = t >> 6;
    const int fr   = lane & 15;
    const int fg   = lane >> 4;

    // QK^T
    bf16x8 qf = *reinterpret_cast<const bf16x8*>(&QK[swz(16 * w + fr, fg * 8)]);
    f32x4 sacc[4];
    #pragma unroll
    for (int nj = 0; nj < 4; ++nj) {
        bf16x8 kf = *reinterpret_cast<const bf16x8*>(&QK[swz(16 * nj + fr, 32 + fg * 8)]);
        sacc[nj] = __builtin_amdgcn_mfma_f32_16x16x32_bf16(qf, kf, (f32x4)0.0f, 0, 0, 0);
    }

    const float scale = 0.17677669529663687f;  // 32^-0.5
    #pragma unroll
    for (int nj = 0; nj < 4; ++nj) {
        #pragma unroll
        for (int j = 0; j < 4; ++j) {
            const int row = 16 * w + fg * 4 + j;
            const int col = 16 * nj + fr;
            const int rn = row < TOK ? row : TOK - 1;
            const int cm = col < TOK ? col : TOK - 1;
            S[row * 80 + col] = sacc[nj][j] * scale + bh_bias[rn * TOK + cm];
        }
    }
    LGKM0_BAR();

    // softmax: 4 threads per row
    {
        const int n = t >> 2, j = t & 3;
        const float* Sr = &S[n * 80];
        float v[16];
        #pragma unroll
        for (int e = 0; e < 8; ++e) v[e]     = Sr[8 * j + e];
        #pragma unroll
        for (int e = 0; e < 8; ++e) v[8 + e] = Sr[32 + 8 * j + e];

        float mx = -1e30f;
        #pragma unroll
        for (int e = 0; e < 8; ++e) mx = fmaxf(mx, v[e]);
        #pragma unroll
        for (int e = 0; e < 8; ++e)
            if (32 + 8 * j + e < TOK) mx = fmaxf(mx, v[8 + e]);
        mx = fmaxf(mx, __shfl_xor(mx, 1, 4));
        mx = fmaxf(mx, __shfl_xor(mx, 2, 4));

        float sum = 0.f;
        #pragma unroll
        for (int e = 0; e < 8; ++e) { v[e] = __expf(v[e] - mx); sum += v[e]; }
        #pragma unroll
        for (int e = 0; e < 8; ++e) {
            const float ev = (32 + 8 * j + e < TOK) ? __expf(v[8 + e] - mx) : 0.f;
            v[8 + e] = ev; sum += ev;
        }
        sum += __shfl_xor(sum, 1, 4);
        sum += __shfl_xor(sum, 2, 4);
        const float inv = 1.f / sum;

        uint4 o;
        o.x = f2bf(v[0] * inv)  | ((unsigned)f2bf(v[1] * inv)  << 16);
        o.y = f2bf(v[2] * inv)  | ((unsigned)f2bf(v[3] * inv)  << 16);
        o.z = f2bf(v[4] * inv)  | ((unsigned)f2bf(v[5] * inv)  << 16);
        o.w = f2bf(v[6] * inv)  | ((unsigned)f2bf(v[7] * inv)  << 16);
        *reinterpret_cast<uint4*>(&Ps[swz(n, 8 * j)]) = o;
        o.x = f2bf(v[8] * inv)  | ((unsigned)f2bf(v[9] * inv)  << 16);
        o.y = f2bf(v[10] * inv) | ((unsigned)f2bf(v[11] * inv) << 16);
        o.z = f2bf(v[12] * inv) | ((unsigned)f2bf(v[13] * inv) << 16);
        o.w = f2bf(v[14] * inv) | ((unsigned)f2bf(v[15] * inv) << 16);
        *reinterpret_cast<uint4*>(&Ps[swz(n, 32 + 8 * j)]) = o;
    }
    LGKM0_BAR();

    // PV
    f32x4 oacc[8];
    #pragma unroll
    for (int nj = 0; nj < 8; ++nj) oacc[nj] = (f32x4)0.0f;
    #pragma unroll
    for (int ks = 0; ks < 2; ++ks) {
        bf16x8 pf = *reinterpret_cast<const bf16x8*>(&Ps[swz(16 * w + fr, ks * 32 + fg * 8)]);
        #pragma unroll
        for (int nj = 0; nj < 8; ++nj) {
            bf16x8 vf = *reinterpret_cast<const bf16x8*>(&V[swzV(16 * nj + fr, ks * 32 + fg * 8)]);
            oacc[nj] = __builtin_amdgcn_mfma_f32_16x16x32_bf16(pf, vf, oacc[nj], 0, 0, 0);
        }
    }

    // ab store, pre-swizzled (T2) for proj-A (validated r10-r13)
    #pragma unroll
    for (int nj = 0; nj < 8; ++nj) {
        const int d = 16 * nj + fr;
        const int c = h * DHEAD + d;
        const int tp = c >> 6, sl = (c >> 3) & 7, cc = c & 7;
        #pragma unroll
        for (int j = 0; j < 4; ++j) {
            const int n = 16 * w + fg * 4 + j;
            if (n < TOK) {
                const int gr = b * TOK + n;
                ab[(size_t)gr * DHTOT + (tp << 6) + (((sl ^ (gr & 7)) << 3) | cc)] = f2bf(oacc[nj][j]);
            }
        }
    }
}

__global__ __launch_bounds__(256)
void attn_mfma(const u16* __restrict__ qkvb,          // [Mc][1536] bf16
               const float* __restrict__ bias_full,   // [NH][49*49]
               u16* __restrict__ ab)                  // [Mc][1024] pre-swz
{
    __shared__ __align__(16) u16  QKs[2][64 * 64];
    __shared__ __align__(16) u16  Vts[2][128 * 64];
    __shared__ __align__(16) float S[64 * 80];
    __shared__ __align__(16) u16  Ps[64 * 64];

    const int t = threadIdx.x;
    const int b = blockIdx.x;
    const u16* base = qkvb + (size_t)b * TOK * HQKV;

    Regs ra, rb;
    load_regs(ra, base + 0 * 192, t);          // head 0 gather in flight

    // zero V pad slots (cols 48..63 regions; gather rewrites col 48 elems only)
    for (int i = t; i < 128 * 2 * 2; i += 256) {
        const int bufi = i >> 9, r = (i >> 1) & 127, sl = 6 + (i & 1);
        *reinterpret_cast<uint4*>(&Vts[bufi][(r << 6) +
            (((sl ^ (r & 7) ^ ((r >> 3) & 7)) & 7) << 3)]) = make_uint4(0, 0, 0, 0);
    }
    LGKM0_BAR();

    #pragma unroll
    for (int hp = 0; hp < 4; ++hp) {
        const int h0 = hp * 2, h1 = hp * 2 + 1;

        write_lds(ra, QKs[0], Vts[0], t);      // auto vmcnt-wait on ra
        load_regs(rb, base + h1 * 192, t);     // next head's loads fly over compute
        LGKM0_BAR();
        attn_head(QKs[0], Vts[0], S, Ps, bias_full + h0 * (TOK * TOK), ab, b, h0, t);

        write_lds(rb, QKs[1], Vts[1], t);
        if (hp < 3) load_regs(ra, base + (h0 + 2) * 192, t);
        LGKM0_BAR();
        attn_head(QKs[1], Vts[1], S, Ps, bias_full + h1 * (TOK * TOK), ab, b, h1, t);
    }
}

// ---------------------------------------------------------------------------
extern "C" void kernel_launch(void* const* d_in, const int* in_sizes, int n_in,
                              void* d_out, int out_size, void* d_ws, size_t ws_size,
                              hipStream_t stream)
{
    const float* x         = (const float*)d_in[0];
    const float* qkv_w     = (const float*)d_in[1];
    const float* qkv_b     = (const float*)d_in[2];
    const float* proj_w    = (const float*)d_in[3];
    const float* proj_b    = (const float*)d_in[4];
    const float* attn_bias = (const float*)d_in[5];
    const int*   bias_idxs = (const int*)d_in[6];

    const int Mtot  = in_sizes[0] / DIMM;            // 100352
    const int Btot  = Mtot / TOK;                    // 2048
    const int n_off = in_sizes[5] / NH;              // 49

    const size_t nWq = (size_t)HQKV * DIMM;
    const size_t nWp = (size_t)DIMM * DHTOT;
    float* bias_full = (float*)d_ws;                           // 76832 B
    u16*   wq        = (u16*)((char*)d_ws + 76832);
    u16*   wp        = wq + nWq;
    u16*   dyn       = wp + nWp;
    const size_t fixed_bytes = 76832 + (nWq + nWp) * sizeof(u16);
    // per-batch: xb 49*384*2 + qkvb 49*1536*2 + ab 49*1024*2
    const size_t per_batch = (size_t)TOK * (DIMM + HQKV + DHTOT) * 2;

    if (ws_size <= fixed_bytes) return;
    long BcL = (long)((ws_size - fixed_bytes) / per_batch);
    int Bc = (int)((BcL / 128) * 128);       // keep Mc multiple of 128
    if (Bc <= 0) return;
    if (Bc > Btot) Bc = Btot;                // single chunk in practice (ws >= 1 GB)

    cast_swz<<<dim3(288), 256, 0, stream>>>(qkv_w, wq, DIMM / 8, (long)HQKV * (DIMM / 8));
    cast_swz<<<dim3(192), 256, 0, stream>>>(proj_w, wp, DHTOT / 8, (long)DIMM * (DHTOT / 8));
    bias_expand<<<dim3((NH * TOK * TOK + 255) / 256), 256, 0, stream>>>(attn_bias, bias_idxs, bias_full, n_off);

    for (int b0 = 0; b0 < Btot; b0 += Bc) {
        const int bc = (b0 + Bc <= Btot) ? Bc : (Btot - b0);   // multiple of 128
        const int Mc = bc * TOK;

        u16* xb   = dyn;
        u16* qkvb = xb   + (size_t)Bc * TOK * DIMM;
        u16* abb  = qkvb + (size_t)Bc * TOK * HQKV;

        const float* xc   = x + (size_t)b0 * TOK * DIMM;
        float*       outc = (float*)d_out + (size_t)b0 * TOK * DIMM;

        cast_swz<<<dim3(2048), 256, 0, stream>>>(xc, xb, DIMM / 8, (long)Mc * (DIMM / 8));

        gemm_qkv<<<dim3((Mc / 128) * (HQKV / 128)), 256, 0, stream>>>(xb, wq, qkv_b, qkvb, Mc);

        attn_mfma<<<dim3(bc), 256, 0, stream>>>(qkvb, bias_full, abb);

        gemm_bf16_nt<<<dim3((Mc / 128) * (DIMM / 128)), 256, 0, stream>>>(abb, wp, proj_b, outc, Mc, DIMM, DHTOT);
    }
}